// Round 17
// baseline (65.499 us; speedup 1.0000x reference)
//
#include <hip/hip_runtime.h>
#include <stdint.h>

// DSN few-shot classifier, MI355X.
// out[q][w] = log_softmax_w( s_w ),  s_w = z_w^T Ghat_w z_w,
// z_w = M_w^T q (raw support dots),  Ghat = G^{-1} - v v^T/(v^T G v).
//
// R16 MEGAFUSION: one fused kernel (128 blocks x 512 threads) does
//   waves 0-4 : R14-proven register/readlane solve, ONE WAY PER WAVE,
//               Ghat -> block LDS (no global Ghat, no straggler wave)
//   all waves : proven MFMA GEMM, 16 queries/wave (128/block), z -> LDS
//   barrier   : threads 0-127: quadratic forms + log_softmax -> out
// Eliminates: Z HBM round-trip (42MB), post kernel, solve-gated kernel tail.
// Spine: prep (~3K cyc) + fused (~8K cyc) at parked clock.
//
// ws layout:
//   [0,    4000)   G : 5*100 double
//   [8192, 172032) P : 80*1024 bf16 (way w rows 16w..16w+9; rest zero)

typedef __attribute__((ext_vector_type(4))) float f32x4;
typedef __attribute__((ext_vector_type(8))) short s16x8;

#define WS_G_OFF    0
#define WS_P_OFF    8192

#define RDL(x, l) __uint_as_float(__builtin_amdgcn_readlane(__float_as_uint(x), (l)))

__device__ __forceinline__ unsigned short f2bf(float f) {
  unsigned int u = __float_as_uint(f);
  u += 0x7FFFu + ((u >> 16) & 1u);   // round-to-nearest-even
  return (unsigned short)(u >> 16);
}

// int64 vs int32 one-hot labels detection (validated R0).
__device__ __forceinline__ bool labels_int64(const int* L) {
  int cnt = 0; bool oddz = true;
  #pragma unroll
  for (int t = 0; t < 20; ++t) {
    int v = L[t];
    if (t & 1) { if (v) oddz = false; }
    else       { if (v) cnt++; }
  }
  return oddz && (cnt == 2);
}

__device__ __forceinline__ int cls_of(const int* L, bool is64, int i) {
  int best = -0x7fffffff, c = 0;
  #pragma unroll
  for (int j = 0; j < 5; ++j) {
    int v = is64 ? L[i * 10 + 2 * j] : L[i * 5 + j];
    if (v > best) { best = v; c = j; }
  }
  return c;
}

// ---- Kernel 1: gram (blocks 0..68) + pack P (blocks 69..148) --------------
__global__ __launch_bounds__(256) void dsn_prep(const float* __restrict__ support,
                                                const int* __restrict__ labels,
                                                double* __restrict__ G,
                                                unsigned short* __restrict__ P) {
  int b = blockIdx.x;
  bool is64 = labels_int64(labels);

  if (b < 69) {                        // ---- gram: one wave per (w,a,b) pair
    int wid  = b * 4 + (threadIdx.x >> 6);
    int lane = threadIdx.x & 63;
    if (wid >= 275) return;
    int w = wid / 55, p = wid % 55;
    int a = 0;
    while (p >= 10 - a) { p -= 10 - a; a++; }
    int bb = a + p;

    int myc = (lane < 50) ? cls_of(labels, is64, lane) : -1;
    unsigned long long mask = __ballot(lane < 50 && myc == w);

    unsigned long long m = mask;
    for (int i = 0; i < a; ++i) m &= m - 1;
    int ia = __ffsll((unsigned long long)m) - 1;
    m = mask;
    for (int i = 0; i < bb; ++i) m &= m - 1;
    int ib = __ffsll((unsigned long long)m) - 1;

    const float* A = support + ia * 1024;
    const float* B = support + ib * 1024;
    double acc = 0.0;
    #pragma unroll
    for (int i = 0; i < 16; ++i) {
      int d = lane + 64 * i;
      acc += (double)A[d] * (double)B[d];
    }
    #pragma unroll
    for (int off = 32; off > 0; off >>= 1) acc += __shfl_xor(acc, off);
    if (lane == 0) {
      G[(w * 10 + a) * 10 + bb] = acc;
      G[(w * 10 + bb) * 10 + a] = acc;
    }
  } else {                             // ---- pack: one block per P row
    int r = b - 69;                    // 0..79
    int w = r >> 4, kk = r & 15;
    int t = threadIdx.x;
    unsigned short* Prow = P + r * 1024;
    if (kk >= 10) {                    // zero-pad rows (block-uniform)
      #pragma unroll
      for (int j = 0; j < 4; ++j) Prow[t + 256 * j] = 0;
      return;
    }
    __shared__ int sid;
    if (t < 64) {
      int myc = (t < 50) ? cls_of(labels, is64, t) : -1;
      unsigned long long mask = __ballot(t < 50 && myc == w);
      if (t == 0) {
        unsigned long long m = mask;
        for (int z = 0; z < kk; ++z) m &= m - 1;
        sid = __ffsll(m) - 1;
      }
    }
    __syncthreads();
    const float* src = support + (size_t)sid * 1024;
    #pragma unroll
    for (int j = 0; j < 4; ++j) Prow[t + 256 * j] = f2bf(src[t + 256 * j]);
  }
}

// ---- Kernel 2: fused solve + GEMM + epilogue ------------------------------
__global__ __launch_bounds__(512) void dsn_fused(const float* __restrict__ query,
                                                 const unsigned short* __restrict__ P,
                                                 const double* __restrict__ G,
                                                 float* __restrict__ out) {
  __shared__ float Gh[500];            // Ghat, all 5 ways
  __shared__ float Zsh[80][132];       // z fragments: 80 rows x 128 queries (+4 pad)

  int t    = threadIdx.x;
  int wave = t >> 6;                   // 0..7
  int lane = t & 63;

  // ===== Phase A: waves 0-4 solve way=wave (R14-proven register solve) =====
  if (wave < 5) {
    int w = wave;
    int li = lane;
    int rr = (li < 10) ? li : 0;
    const double* Gr = G + w * 100 + rr * 10;

    float o[10], g[10], h[10];
    #pragma unroll
    for (int j = 0; j < 10; ++j) {
      o[j] = (float)Gr[j];
      g[j] = o[j];
      h[j] = (li == j) ? 1.f : 0.f;
    }

    // Gauss-Jordan on [G | I] (SPD): h -> G^{-1} row li
    #pragma unroll
    for (int k = 0; k < 10; ++k) {
      float piv = 1.f / RDL(g[k], k);
      float pg[10], ph[10];
      #pragma unroll
      for (int j = 0; j < 10; ++j) {
        pg[j] = RDL(g[j], k) * piv;
        ph[j] = RDL(h[j], k) * piv;
      }
      float f = g[k];
      bool isk = (li == k);
      #pragma unroll
      for (int j = 0; j < 10; ++j) {
        g[j] = isk ? pg[j] : g[j] - f * pg[j];
        h[j] = isk ? ph[j] : h[j] - f * ph[j];
      }
    }

    // b = Ginv / diagmax
    float b[10];
    float d = h[0];
    #pragma unroll
    for (int k = 1; k < 10; ++k) d = (li == k) ? h[k] : d;
    float dm = RDL(d, 0);
    #pragma unroll
    for (int k = 1; k < 10; ++k) dm = fmaxf(dm, RDL(d, k));
    float rn = 1.f / dm;
    #pragma unroll
    for (int j = 0; j < 10; ++j) b[j] = h[j] * rn;

    // 7 diag-renormalized squarings -> dominant eigendirection of Ginv
    #pragma unroll
    for (int sq = 0; sq < 7; ++sq) {
      float c[10];
      #pragma unroll
      for (int j = 0; j < 10; ++j) {
        float s = 0.f;
        #pragma unroll
        for (int k = 0; k < 10; ++k) s += b[k] * RDL(b[j], k);
        c[j] = s;
      }
      float dd = c[0];
      #pragma unroll
      for (int k = 1; k < 10; ++k) dd = (li == k) ? c[k] : dd;
      float m = RDL(dd, 0);
      #pragma unroll
      for (int k = 1; k < 10; ++k) m = fmaxf(m, RDL(dd, k));
      float rm = 1.f / m;
      #pragma unroll
      for (int j = 0; j < 10; ++j) b[j] = c[j] * rm;
    }

    // v = dominant column (argmax diag) + 2 refine matvecs
    float db = b[0];
    #pragma unroll
    for (int k = 1; k < 10; ++k) db = (li == k) ? b[k] : db;
    int jmx = 0;
    float bv = RDL(db, 0);
    #pragma unroll
    for (int k = 1; k < 10; ++k) {
      float t2 = RDL(db, k);
      if (t2 > bv) { bv = t2; jmx = k; }   // uniform
    }
    float v = b[0];
    #pragma unroll
    for (int k = 1; k < 10; ++k) v = (jmx == k) ? b[k] : v;
    #pragma unroll
    for (int rf = 0; rf < 2; ++rf) {
      float nv = 0.f;
      #pragma unroll
      for (int k = 0; k < 10; ++k) nv += b[k] * RDL(v, k);
      v = nv;
    }

    // denom = v^T G v; Ghat = Ginv - v v^T / denom  -> LDS
    float gv = 0.f;
    #pragma unroll
    for (int k = 0; k < 10; ++k) gv += o[k] * RDL(v, k);
    float tn = v * gv;
    float denom = RDL(tn, 0);
    #pragma unroll
    for (int k = 1; k < 10; ++k) denom += RDL(tn, k);
    float rden = 1.f / denom;
    float vj[10];
    #pragma unroll
    for (int j = 0; j < 10; ++j) vj[j] = RDL(v, j);
    if (li < 10) {
      #pragma unroll
      for (int j = 0; j < 10; ++j)
        Gh[w * 100 + li * 10 + j] = h[j] - v * vj[j] * rden;
    }
  }

  // ===== Phase B: all waves GEMM (16 queries each; proven shape) ==========
  {
    int q0   = blockIdx.x * 128 + wave * 16;
    int qrow = lane & 15;
    int kbase = (lane >> 4) * 8;

    const float* qp = query + (size_t)(q0 + qrow) * 1024 + kbase;
    const unsigned short* up = P + qrow * 1024 + kbase;

    f32x4 acc[5];
    #pragma unroll
    for (int w = 0; w < 5; ++w) acc[w] = (f32x4){0.f, 0.f, 0.f, 0.f};

    #pragma unroll 4
    for (int kt = 0; kt < 32; ++kt) {
      const float* qk = qp + kt * 32;
      f32x4 lo = *(const f32x4*)qk;
      f32x4 hi = *(const f32x4*)(qk + 4);
      s16x8 bf;
      bf[0] = (short)f2bf(lo[0]); bf[1] = (short)f2bf(lo[1]);
      bf[2] = (short)f2bf(lo[2]); bf[3] = (short)f2bf(lo[3]);
      bf[4] = (short)f2bf(hi[0]); bf[5] = (short)f2bf(hi[1]);
      bf[6] = (short)f2bf(hi[2]); bf[7] = (short)f2bf(hi[3]);
      const unsigned short* uk = up + kt * 32;
      #pragma unroll
      for (int w = 0; w < 5; ++w) {
        s16x8 av = *(const s16x8*)(uk + w * 16384);   // row w*16 + qrow
        acc[w] = __builtin_amdgcn_mfma_f32_16x16x32_bf16(av, bf, acc[w], 0, 0, 0);
      }
    }

    // park z in LDS: D[row=s][col=q]; row=(lane>>4)*4+reg, col=lane&15 (m89)
    int rowbase = (lane >> 4) * 4;
    int qcol = wave * 16 + qrow;
    #pragma unroll
    for (int w = 0; w < 5; ++w) {
      #pragma unroll
      for (int r = 0; r < 4; ++r)
        Zsh[w * 16 + rowbase + r][qcol] = acc[w][r];
    }
  }
  __syncthreads();

  // ===== Phase C: epilogue, threads 0-127 (one query each) ================
  if (t < 128) {
    int q = blockIdx.x * 128 + t;
    float zv[50];
    #pragma unroll
    for (int w = 0; w < 5; ++w)
      #pragma unroll
      for (int s = 0; s < 10; ++s)
        zv[w * 10 + s] = Zsh[w * 16 + s][t];

    float sv[5];
    #pragma unroll
    for (int w = 0; w < 5; ++w) {
      float s = 0.f;
      #pragma unroll
      for (int i = 0; i < 10; ++i) {
        float gz = 0.f;
        #pragma unroll
        for (int j = 0; j < 10; ++j) gz += Gh[w * 100 + i * 10 + j] * zv[w * 10 + j];
        s += zv[w * 10 + i] * gz;
      }
      sv[w] = s;
    }
    float mx = fmaxf(fmaxf(fmaxf(sv[0], sv[1]), fmaxf(sv[2], sv[3])), sv[4]);
    float sum = 0.f;
    #pragma unroll
    for (int w = 0; w < 5; ++w) sum += expf(sv[w] - mx);
    float lse = mx + logf(sum);
    float* o = out + (size_t)q * 5;
    #pragma unroll
    for (int w = 0; w < 5; ++w) o[w] = sv[w] - lse;
  }
}

extern "C" void kernel_launch(void* const* d_in, const int* in_sizes, int n_in,
                              void* d_out, int out_size, void* d_ws, size_t ws_size,
                              hipStream_t stream) {
  const float* support = (const float*)d_in[0];
  const int*   labels  = (const int*)d_in[1];
  const float* query   = (const float*)d_in[2];
  float* out = (float*)d_out;
  char* ws = (char*)d_ws;

  double*         G = (double*)(ws + WS_G_OFF);
  unsigned short* P = (unsigned short*)(ws + WS_P_OFF);

  int nq = in_sizes[2] / 1024;          // 16384
  int fused_blocks = nq / 128;          // 128

  hipLaunchKernelGGL(dsn_prep,  dim3(149), dim3(256), 0, stream, support, labels, G, P);
  hipLaunchKernelGGL(dsn_fused, dim3(fused_blocks), dim3(512), 0, stream,
                     query, P, G, out);
}

// Round 18
// 61.845 us; speedup vs baseline: 1.0591x; 1.0591x over previous
//
#include <hip/hip_runtime.h>
#include <stdint.h>

// DSN few-shot classifier, MI355X.
// out[q][w] = log_softmax_w( s_w ),  s_w = z_w^T Ghat_w z_w,
// z_w = M_w^T q (raw support dots),  Ghat = G^{-1} - v v^T/(v^T G v).
//
// R17: (a) GEMM unroll 4->8 (halve serial load-latency exposures: the timed
// bottleneck per R13/R14-vs-R15/R16 attribution); (b) z stays in LDS, epilogue
// fused into the GEMM block (deletes 42MB Z round-trip + post kernel);
// (c) solve = blocks 0..4 (R14 register/readlane solve, proven), publishing
// Ghat + device-scope flag; GEMM blocks compute z FIRST, then spin (solve
// long done), fence, stage Ghat, epilogue. prep zeroes the flag every call.
//
// ws layout:
//   [0,    4000)   G    : 5*100 double
//   [4096, 6096)   Ghat : 5*100 float
//   [6144, 6148)   flag : int (solve-done count; prep zeroes each call)
//   [8192, 172032) P    : 80*1024 bf16 (way w rows 16w..16w+9; rest zero)

typedef __attribute__((ext_vector_type(4))) float f32x4;
typedef __attribute__((ext_vector_type(8))) short s16x8;

#define WS_G_OFF    0
#define WS_GH_OFF   4096
#define WS_FLAG_OFF 6144
#define WS_P_OFF    8192

#define RDL(x, l) __uint_as_float(__builtin_amdgcn_readlane(__float_as_uint(x), (l)))

__device__ __forceinline__ unsigned short f2bf(float f) {
  unsigned int u = __float_as_uint(f);
  u += 0x7FFFu + ((u >> 16) & 1u);   // round-to-nearest-even
  return (unsigned short)(u >> 16);
}

// int64 vs int32 one-hot labels detection (validated R0).
__device__ __forceinline__ bool labels_int64(const int* L) {
  int cnt = 0; bool oddz = true;
  #pragma unroll
  for (int t = 0; t < 20; ++t) {
    int v = L[t];
    if (t & 1) { if (v) oddz = false; }
    else       { if (v) cnt++; }
  }
  return oddz && (cnt == 2);
}

__device__ __forceinline__ int cls_of(const int* L, bool is64, int i) {
  int best = -0x7fffffff, c = 0;
  #pragma unroll
  for (int j = 0; j < 5; ++j) {
    int v = is64 ? L[i * 10 + 2 * j] : L[i * 5 + j];
    if (v > best) { best = v; c = j; }
  }
  return c;
}

// ---- Kernel 1: gram (0..68) + pack P (69..148) + flag zero (149) ----------
__global__ __launch_bounds__(256) void dsn_prep(const float* __restrict__ support,
                                                const int* __restrict__ labels,
                                                double* __restrict__ G,
                                                unsigned short* __restrict__ P,
                                                int* __restrict__ flag) {
  int b = blockIdx.x;
  if (b == 149) {                      // ---- flag reset (deterministic spin)
    if (threadIdx.x == 0) *flag = 0;
    return;
  }
  bool is64 = labels_int64(labels);

  if (b < 69) {                        // ---- gram: one wave per (w,a,b) pair
    int wid  = b * 4 + (threadIdx.x >> 6);
    int lane = threadIdx.x & 63;
    if (wid >= 275) return;
    int w = wid / 55, p = wid % 55;
    int a = 0;
    while (p >= 10 - a) { p -= 10 - a; a++; }
    int bb = a + p;

    int myc = (lane < 50) ? cls_of(labels, is64, lane) : -1;
    unsigned long long mask = __ballot(lane < 50 && myc == w);

    unsigned long long m = mask;
    for (int i = 0; i < a; ++i) m &= m - 1;
    int ia = __ffsll((unsigned long long)m) - 1;
    m = mask;
    for (int i = 0; i < bb; ++i) m &= m - 1;
    int ib = __ffsll((unsigned long long)m) - 1;

    const float* A = support + ia * 1024;
    const float* B = support + ib * 1024;
    double acc = 0.0;
    #pragma unroll
    for (int i = 0; i < 16; ++i) {
      int d = lane + 64 * i;
      acc += (double)A[d] * (double)B[d];
    }
    #pragma unroll
    for (int off = 32; off > 0; off >>= 1) acc += __shfl_xor(acc, off);
    if (lane == 0) {
      G[(w * 10 + a) * 10 + bb] = acc;
      G[(w * 10 + bb) * 10 + a] = acc;
    }
  } else {                             // ---- pack: one block per P row
    int r = b - 69;                    // 0..79
    int w = r >> 4, kk = r & 15;
    int t = threadIdx.x;
    unsigned short* Prow = P + r * 1024;
    if (kk >= 10) {                    // zero-pad rows (block-uniform)
      #pragma unroll
      for (int j = 0; j < 4; ++j) Prow[t + 256 * j] = 0;
      return;
    }
    __shared__ int sid;
    if (t < 64) {
      int myc = (t < 50) ? cls_of(labels, is64, t) : -1;
      unsigned long long mask = __ballot(t < 50 && myc == w);
      if (t == 0) {
        unsigned long long m = mask;
        for (int z = 0; z < kk; ++z) m &= m - 1;
        sid = __ffsll(m) - 1;
      }
    }
    __syncthreads();
    const float* src = support + (size_t)sid * 1024;
    #pragma unroll
    for (int j = 0; j < 4; ++j) Prow[t + 256 * j] = f2bf(src[t + 256 * j]);
  }
}

// ---- Kernel 2: solve (blocks 0..4) + GEMM+epilogue (blocks 5..260) --------
__global__ __launch_bounds__(256) void dsn_zs(const float* __restrict__ query,
                                              const unsigned short* __restrict__ P,
                                              const double* __restrict__ G,
                                              float* __restrict__ Ghat,
                                              int* __restrict__ flag,
                                              float* __restrict__ out) {
  if (blockIdx.x < 5) {
    // ====== solve, register-only, barrier-free (wave 0; R14 proven) =======
    if (threadIdx.x >= 64) return;
    int w = blockIdx.x;
    int li = threadIdx.x;
    int rr = (li < 10) ? li : 0;
    const double* Gr = G + w * 100 + rr * 10;

    float o[10], g[10], h[10];
    #pragma unroll
    for (int j = 0; j < 10; ++j) {
      o[j] = (float)Gr[j];
      g[j] = o[j];
      h[j] = (li == j) ? 1.f : 0.f;
    }

    // Gauss-Jordan on [G | I] (SPD): h -> G^{-1} row li
    #pragma unroll
    for (int k = 0; k < 10; ++k) {
      float piv = 1.f / RDL(g[k], k);
      float pg[10], ph[10];
      #pragma unroll
      for (int j = 0; j < 10; ++j) {
        pg[j] = RDL(g[j], k) * piv;
        ph[j] = RDL(h[j], k) * piv;
      }
      float f = g[k];
      bool isk = (li == k);
      #pragma unroll
      for (int j = 0; j < 10; ++j) {
        g[j] = isk ? pg[j] : g[j] - f * pg[j];
        h[j] = isk ? ph[j] : h[j] - f * ph[j];
      }
    }

    // b = Ginv / diagmax
    float b[10];
    float d = h[0];
    #pragma unroll
    for (int k = 1; k < 10; ++k) d = (li == k) ? h[k] : d;
    float dm = RDL(d, 0);
    #pragma unroll
    for (int k = 1; k < 10; ++k) dm = fmaxf(dm, RDL(d, k));
    float rn = 1.f / dm;
    #pragma unroll
    for (int j = 0; j < 10; ++j) b[j] = h[j] * rn;

    // 7 diag-renormalized squarings -> dominant eigendirection of Ginv
    #pragma unroll
    for (int sq = 0; sq < 7; ++sq) {
      float c[10];
      #pragma unroll
      for (int j = 0; j < 10; ++j) {
        float s = 0.f;
        #pragma unroll
        for (int k = 0; k < 10; ++k) s += b[k] * RDL(b[j], k);
        c[j] = s;
      }
      float dd = c[0];
      #pragma unroll
      for (int k = 1; k < 10; ++k) dd = (li == k) ? c[k] : dd;
      float m = RDL(dd, 0);
      #pragma unroll
      for (int k = 1; k < 10; ++k) m = fmaxf(m, RDL(dd, k));
      float rm = 1.f / m;
      #pragma unroll
      for (int j = 0; j < 10; ++j) b[j] = c[j] * rm;
    }

    // v = dominant column (argmax diag) + 2 refine matvecs
    float db = b[0];
    #pragma unroll
    for (int k = 1; k < 10; ++k) db = (li == k) ? b[k] : db;
    int jmx = 0;
    float bv = RDL(db, 0);
    #pragma unroll
    for (int k = 1; k < 10; ++k) {
      float t2 = RDL(db, k);
      if (t2 > bv) { bv = t2; jmx = k; }   // uniform
    }
    float v = b[0];
    #pragma unroll
    for (int k = 1; k < 10; ++k) v = (jmx == k) ? b[k] : v;
    #pragma unroll
    for (int rf = 0; rf < 2; ++rf) {
      float nv = 0.f;
      #pragma unroll
      for (int k = 0; k < 10; ++k) nv += b[k] * RDL(v, k);
      v = nv;
    }

    // denom = v^T G v; Ghat = Ginv - v v^T / denom
    float gv = 0.f;
    #pragma unroll
    for (int k = 0; k < 10; ++k) gv += o[k] * RDL(v, k);
    float tn = v * gv;
    float denom = RDL(tn, 0);
    #pragma unroll
    for (int k = 1; k < 10; ++k) denom += RDL(tn, k);
    float rden = 1.f / denom;
    if (li < 10) {
      #pragma unroll
      for (int j = 0; j < 10; ++j)
        Ghat[w * 100 + li * 10 + j] = h[j] - v * RDL(v, j) * rden;
    }
    if (li == 0) {                     // release: Ghat visible, then count up
      __threadfence();
      atomicAdd(flag, 1);
    }
    return;
  }

  // ====== GEMM + fused epilogue: 4 waves x 16 queries = 64 q/block ========
  __shared__ float Zsh[4][80][16];     // per-wave z slabs (20 KB)
  __shared__ float Ghs[500];

  int t    = threadIdx.x;
  int wave = t >> 6;
  int lane = t & 63;
  int gb   = blockIdx.x - 5;           // 0..255
  int q0   = (gb * 4 + wave) * 16;
  int qrow = lane & 15;
  int kbase = (lane >> 4) * 8;

  const float* qp = query + (size_t)(q0 + qrow) * 1024 + kbase;
  const unsigned short* up = P + qrow * 1024 + kbase;

  f32x4 acc[5];
  #pragma unroll
  for (int w = 0; w < 5; ++w) acc[w] = (f32x4){0.f, 0.f, 0.f, 0.f};

  #pragma unroll 8
  for (int kt = 0; kt < 32; ++kt) {
    const float* qk = qp + kt * 32;
    f32x4 lo = *(const f32x4*)qk;
    f32x4 hi = *(const f32x4*)(qk + 4);
    s16x8 bf;
    bf[0] = (short)f2bf(lo[0]); bf[1] = (short)f2bf(lo[1]);
    bf[2] = (short)f2bf(lo[2]); bf[3] = (short)f2bf(lo[3]);
    bf[4] = (short)f2bf(hi[0]); bf[5] = (short)f2bf(hi[1]);
    bf[6] = (short)f2bf(hi[2]); bf[7] = (short)f2bf(hi[3]);
    const unsigned short* uk = up + kt * 32;
    #pragma unroll
    for (int w = 0; w < 5; ++w) {
      s16x8 av = *(const s16x8*)(uk + w * 16384);   // row w*16 + qrow
      acc[w] = __builtin_amdgcn_mfma_f32_16x16x32_bf16(av, bf, acc[w], 0, 0, 0);
    }
  }

  // park z: D[row=s][col=q]; row=(lane>>4)*4+reg, col=lane&15 (m89)
  int rowbase = (lane >> 4) * 4;
  #pragma unroll
  for (int w = 0; w < 5; ++w) {
    #pragma unroll
    for (int r = 0; r < 4; ++r)
      Zsh[wave][w * 16 + rowbase + r][qrow] = acc[w][r];
  }

  // wait for solve (long since done in the common case)
  if (t == 0) {
    while (atomicAdd(flag, 0) < 5) __builtin_amdgcn_s_sleep(8);
  }
  __syncthreads();
  __threadfence();                     // acquire before reading Ghat
  // stage Ghat (atomic reads -> coherent across XCD L2s)
  if (t < 250) {
    Ghs[t]       = atomicAdd(&Ghat[t], 0.f);
    Ghs[t + 250] = atomicAdd(&Ghat[t + 250], 0.f);
  }
  __syncthreads();

  // epilogue: threads 0-63, one query each
  if (t < 64) {
    int q = gb * 64 + t;
    int sl = t >> 4, col = t & 15;
    float zv[50];
    #pragma unroll
    for (int w = 0; w < 5; ++w)
      #pragma unroll
      for (int s = 0; s < 10; ++s)
        zv[w * 10 + s] = Zsh[sl][w * 16 + s][col];

    float sv[5];
    #pragma unroll
    for (int w = 0; w < 5; ++w) {
      float s = 0.f;
      #pragma unroll
      for (int i = 0; i < 10; ++i) {
        float gz = 0.f;
        #pragma unroll
        for (int j = 0; j < 10; ++j) gz += Ghs[w * 100 + i * 10 + j] * zv[w * 10 + j];
        s += zv[w * 10 + i] * gz;
      }
      sv[w] = s;
    }
    float mx = fmaxf(fmaxf(fmaxf(sv[0], sv[1]), fmaxf(sv[2], sv[3])), sv[4]);
    float sum = 0.f;
    #pragma unroll
    for (int w = 0; w < 5; ++w) sum += expf(sv[w] - mx);
    float lse = mx + logf(sum);
    float* o = out + (size_t)q * 5;
    #pragma unroll
    for (int w = 0; w < 5; ++w) o[w] = sv[w] - lse;
  }
}

extern "C" void kernel_launch(void* const* d_in, const int* in_sizes, int n_in,
                              void* d_out, int out_size, void* d_ws, size_t ws_size,
                              hipStream_t stream) {
  const float* support = (const float*)d_in[0];
  const int*   labels  = (const int*)d_in[1];
  const float* query   = (const float*)d_in[2];
  float* out = (float*)d_out;
  char* ws = (char*)d_ws;

  double*         G    = (double*)(ws + WS_G_OFF);
  float*          Ghat = (float*)(ws + WS_GH_OFF);
  int*            flag = (int*)(ws + WS_FLAG_OFF);
  unsigned short* P    = (unsigned short*)(ws + WS_P_OFF);

  int nq = in_sizes[2] / 1024;          // 16384
  int zs_blocks = nq / 64 + 5;          // 256 GEMM blocks + 5 solve

  hipLaunchKernelGGL(dsn_prep, dim3(150), dim3(256), 0, stream,
                     support, labels, G, P, flag);
  hipLaunchKernelGGL(dsn_zs,   dim3(zs_blocks), dim3(256), 0, stream,
                     query, P, G, Ghat, flag, out);
}

// Round 19
// 55.895 us; speedup vs baseline: 1.1718x; 1.1065x over previous
//
#include <hip/hip_runtime.h>
#include <stdint.h>

// DSN few-shot classifier, MI355X.
// out[q][w] = log_softmax_w( s_w ),  s_w = z_w^T Ghat_w z_w,
// z_w = M_w^T q (raw support dots),  Ghat = G^{-1} - v v^T/(v^T G v).
//
// R18: (a) K1 = pack (blocks 0-79, proven) + PER-WAY gram+solve blocks 80-84
// (R5's in-block LDS gram + R14's register/readlane solve) -> Ghat; kernel
// boundary = coherence, NO flags/atomics/spins. (b) K2 = split-K-in-LDS GEMM:
// block=16 queries, 4 waves = 4 K-splits of 256 (8 fully-unrolled kt steps),
// partials in padded LDS, fused epilogue. 1024 blocks = 4 blocks/CU = 4
// waves/SIMD (R15's occupancy win) with ZERO extra HBM traffic (R15's
// regression cause) and none of R17's atomic staging.
//
// ws layout:
//   [0,    2048)   Ghat : 5*100 float
//   [8192, 172032) P    : 80*1024 bf16 (way w rows 16w..16w+9; rest zero)

typedef __attribute__((ext_vector_type(4))) float f32x4;
typedef __attribute__((ext_vector_type(8))) short s16x8;

#define WS_GH_OFF   0
#define WS_P_OFF    8192

#define RDL(x, l) __uint_as_float(__builtin_amdgcn_readlane(__float_as_uint(x), (l)))

__device__ __forceinline__ unsigned short f2bf(float f) {
  unsigned int u = __float_as_uint(f);
  u += 0x7FFFu + ((u >> 16) & 1u);   // round-to-nearest-even
  return (unsigned short)(u >> 16);
}

// int64 vs int32 one-hot labels detection (validated R0).
__device__ __forceinline__ bool labels_int64(const int* L) {
  int cnt = 0; bool oddz = true;
  #pragma unroll
  for (int t = 0; t < 20; ++t) {
    int v = L[t];
    if (t & 1) { if (v) oddz = false; }
    else       { if (v) cnt++; }
  }
  return oddz && (cnt == 2);
}

__device__ __forceinline__ int cls_of(const int* L, bool is64, int i) {
  int best = -0x7fffffff, c = 0;
  #pragma unroll
  for (int j = 0; j < 5; ++j) {
    int v = is64 ? L[i * 10 + 2 * j] : L[i * 5 + j];
    if (v > best) { best = v; c = j; }
  }
  return c;
}

// ---- Kernel 1: pack P (blocks 0..79) + gram+solve (blocks 80..84) ---------
__global__ __launch_bounds__(256) void dsn_prep(const float* __restrict__ support,
                                                const int* __restrict__ labels,
                                                unsigned short* __restrict__ P,
                                                float* __restrict__ Ghat) {
  int b = blockIdx.x;
  int t = threadIdx.x;
  bool is64 = labels_int64(labels);

  if (b < 80) {                        // ---- pack: one block per P row
    int r = b;                         // 0..79
    int w = r >> 4, kk = r & 15;
    unsigned short* Prow = P + r * 1024;
    if (kk >= 10) {                    // zero-pad rows (block-uniform)
      #pragma unroll
      for (int j = 0; j < 4; ++j) Prow[t + 256 * j] = 0;
      return;
    }
    __shared__ int sid;
    if (t < 64) {
      int myc = (t < 50) ? cls_of(labels, is64, t) : -1;
      unsigned long long mask = __ballot(t < 50 && myc == w);
      if (t == 0) {
        unsigned long long m = mask;
        for (int z = 0; z < kk; ++z) m &= m - 1;
        sid = __ffsll(m) - 1;
      }
    }
    __syncthreads();
    const float* src = support + (size_t)sid * 1024;
    #pragma unroll
    for (int j = 0; j < 4; ++j) Prow[t + 256 * j] = f2bf(src[t + 256 * j]);
    return;
  }

  // ---- gram + solve for way w = b-80 (self-contained; R5 gram + R14 solve)
  int w = b - 80;
  __shared__ float sup[10][1024];      // 40 KB: this way's support rows
  __shared__ float Gf[100];
  __shared__ int   ids[10];

  if (t < 64) {
    int myc = (t < 50) ? cls_of(labels, is64, t) : -1;
    unsigned long long mask = __ballot(t < 50 && myc == w);
    if (t < 10) {
      unsigned long long m = mask;
      for (int z = 0; z < t; ++z) m &= m - 1;
      ids[t] = __ffsll(m) - 1;
    }
  }
  __syncthreads();

  #pragma unroll 1
  for (int s = 0; s < 10; ++s) {
    const float* src = support + (size_t)ids[s] * 1024;
    #pragma unroll
    for (int j = 0; j < 4; ++j) sup[s][t + 256 * j] = src[t + 256 * j];
  }
  __syncthreads();

  {                                    // gram: wave v handles pairs v, v+4, ..
    int wv = t >> 6, lane = t & 63;
    #pragma unroll 1
    for (int p = wv; p < 55; p += 4) {
      int a2 = 0, pp = p;
      while (pp >= 10 - a2) { pp -= 10 - a2; a2++; }
      int b2 = a2 + pp;
      double acc = 0.0;
      #pragma unroll
      for (int i2 = 0; i2 < 16; ++i2) {
        int d = lane + 64 * i2;
        acc += (double)sup[a2][d] * (double)sup[b2][d];
      }
      #pragma unroll
      for (int off = 32; off > 0; off >>= 1) acc += __shfl_xor(acc, off);
      if (lane == 0) {
        Gf[a2 * 10 + b2] = (float)acc;
        Gf[b2 * 10 + a2] = (float)acc;
      }
    }
  }
  __syncthreads();

  // register/readlane solve on wave 0 (R14 proven; Gf from LDS)
  if (t >= 64) return;
  int li = t;
  int rr = (li < 10) ? li : 0;

  float o[10], g[10], h[10];
  #pragma unroll
  for (int j = 0; j < 10; ++j) {
    o[j] = Gf[rr * 10 + j];
    g[j] = o[j];
    h[j] = (li == j) ? 1.f : 0.f;
  }

  // Gauss-Jordan on [G | I] (SPD): h -> G^{-1} row li
  #pragma unroll
  for (int k = 0; k < 10; ++k) {
    float piv = 1.f / RDL(g[k], k);
    float pg[10], ph[10];
    #pragma unroll
    for (int j = 0; j < 10; ++j) {
      pg[j] = RDL(g[j], k) * piv;
      ph[j] = RDL(h[j], k) * piv;
    }
    float f = g[k];
    bool isk = (li == k);
    #pragma unroll
    for (int j = 0; j < 10; ++j) {
      g[j] = isk ? pg[j] : g[j] - f * pg[j];
      h[j] = isk ? ph[j] : h[j] - f * ph[j];
    }
  }

  // bmat = Ginv / diagmax
  float bmat[10];
  float d = h[0];
  #pragma unroll
  for (int k = 1; k < 10; ++k) d = (li == k) ? h[k] : d;
  float dm = RDL(d, 0);
  #pragma unroll
  for (int k = 1; k < 10; ++k) dm = fmaxf(dm, RDL(d, k));
  float rn = 1.f / dm;
  #pragma unroll
  for (int j = 0; j < 10; ++j) bmat[j] = h[j] * rn;

  // 7 diag-renormalized squarings -> dominant eigendirection of Ginv
  #pragma unroll
  for (int sq = 0; sq < 7; ++sq) {
    float c[10];
    #pragma unroll
    for (int j = 0; j < 10; ++j) {
      float s = 0.f;
      #pragma unroll
      for (int k = 0; k < 10; ++k) s += bmat[k] * RDL(bmat[j], k);
      c[j] = s;
    }
    float dd = c[0];
    #pragma unroll
    for (int k = 1; k < 10; ++k) dd = (li == k) ? c[k] : dd;
    float m = RDL(dd, 0);
    #pragma unroll
    for (int k = 1; k < 10; ++k) m = fmaxf(m, RDL(dd, k));
    float rm = 1.f / m;
    #pragma unroll
    for (int j = 0; j < 10; ++j) bmat[j] = c[j] * rm;
  }

  // v = dominant column (argmax diag) + 2 refine matvecs
  float db = bmat[0];
  #pragma unroll
  for (int k = 1; k < 10; ++k) db = (li == k) ? bmat[k] : db;
  int jmx = 0;
  float bv = RDL(db, 0);
  #pragma unroll
  for (int k = 1; k < 10; ++k) {
    float t2 = RDL(db, k);
    if (t2 > bv) { bv = t2; jmx = k; }   // uniform
  }
  float v = bmat[0];
  #pragma unroll
  for (int k = 1; k < 10; ++k) v = (jmx == k) ? bmat[k] : v;
  #pragma unroll
  for (int rf = 0; rf < 2; ++rf) {
    float nv = 0.f;
    #pragma unroll
    for (int k = 0; k < 10; ++k) nv += bmat[k] * RDL(v, k);
    v = nv;
  }

  // denom = v^T G v; Ghat = Ginv - v v^T / denom
  float gv = 0.f;
  #pragma unroll
  for (int k = 0; k < 10; ++k) gv += o[k] * RDL(v, k);
  float tn = v * gv;
  float denom = RDL(tn, 0);
  #pragma unroll
  for (int k = 1; k < 10; ++k) denom += RDL(tn, k);
  float rden = 1.f / denom;
  if (li < 10) {
    #pragma unroll
    for (int j = 0; j < 10; ++j)
      Ghat[w * 100 + li * 10 + j] = h[j] - v * RDL(v, j) * rden;
  }
}

// ---- Kernel 2: split-K-in-LDS GEMM + fused epilogue -----------------------
// Block = 16 queries; wave = one 256-elem K-split (8 fully-unrolled kt).
// 1024 blocks -> 4 blocks/CU -> 4 waves/SIMD.
__global__ __launch_bounds__(256, 4) void dsn_main(const float* __restrict__ query,
                                                   const unsigned short* __restrict__ P,
                                                   const float* __restrict__ Ghat,
                                                   float* __restrict__ out) {
  __shared__ float Zsh[4][80][17];     // padded: conflict-free park/read
  __shared__ float Ghs[500];

  int t    = threadIdx.x;
  int wave = t >> 6;                   // K-split 0..3
  int lane = t & 63;
  int q0   = blockIdx.x * 16;
  int qrow = lane & 15;
  int kbase = wave * 256 + (lane >> 4) * 8;

  // stage Ghat (plain loads; kernel-boundary coherent, L3-broadcast)
  if (t < 250) {
    Ghs[t]       = Ghat[t];
    Ghs[t + 250] = Ghat[t + 250];
  }

  const float* qp = query + (size_t)(q0 + qrow) * 1024 + kbase;
  const unsigned short* up = P + qrow * 1024 + kbase;

  f32x4 acc[5];
  #pragma unroll
  for (int w = 0; w < 5; ++w) acc[w] = (f32x4){0.f, 0.f, 0.f, 0.f};

  #pragma unroll
  for (int kt = 0; kt < 8; ++kt) {     // 256 K-elems, fully unrolled
    const float* qk = qp + kt * 32;
    f32x4 lo = *(const f32x4*)qk;
    f32x4 hi = *(const f32x4*)(qk + 4);
    s16x8 bf;
    bf[0] = (short)f2bf(lo[0]); bf[1] = (short)f2bf(lo[1]);
    bf[2] = (short)f2bf(lo[2]); bf[3] = (short)f2bf(lo[3]);
    bf[4] = (short)f2bf(hi[0]); bf[5] = (short)f2bf(hi[1]);
    bf[6] = (short)f2bf(hi[2]); bf[7] = (short)f2bf(hi[3]);
    const unsigned short* uk = up + kt * 32;
    #pragma unroll
    for (int w = 0; w < 5; ++w) {
      s16x8 av = *(const s16x8*)(uk + w * 16384);   // row w*16 + qrow
      acc[w] = __builtin_amdgcn_mfma_f32_16x16x32_bf16(av, bf, acc[w], 0, 0, 0);
    }
  }

  // park partial z: D[row=s][col=q]; row=(lane>>4)*4+reg, col=lane&15 (m89)
  int rowbase = (lane >> 4) * 4;
  #pragma unroll
  for (int w = 0; w < 5; ++w) {
    #pragma unroll
    for (int r = 0; r < 4; ++r)
      Zsh[wave][w * 16 + rowbase + r][qrow] = acc[w][r];
  }
  __syncthreads();

  // epilogue: threads 0-15, one query each (sum splits deterministically)
  if (t < 16) {
    int q = q0 + t;
    float zv[50];
    #pragma unroll
    for (int w = 0; w < 5; ++w) {
      #pragma unroll
      for (int s = 0; s < 10; ++s) {
        float z = Zsh[0][w * 16 + s][t];
        #pragma unroll
        for (int sp = 1; sp < 4; ++sp) z += Zsh[sp][w * 16 + s][t];
        zv[w * 10 + s] = z;
      }
    }
    float sv[5];
    #pragma unroll
    for (int w = 0; w < 5; ++w) {
      float s = 0.f;
      #pragma unroll
      for (int i = 0; i < 10; ++i) {
        float gz = 0.f;
        #pragma unroll
        for (int j = 0; j < 10; ++j) gz += Ghs[w * 100 + i * 10 + j] * zv[w * 10 + j];
        s += zv[w * 10 + i] * gz;
      }
      sv[w] = s;
    }
    float mx = fmaxf(fmaxf(fmaxf(sv[0], sv[1]), fmaxf(sv[2], sv[3])), sv[4]);
    float sum = 0.f;
    #pragma unroll
    for (int w = 0; w < 5; ++w) sum += expf(sv[w] - mx);
    float lse = mx + logf(sum);
    float* o = out + (size_t)q * 5;
    #pragma unroll
    for (int w = 0; w < 5; ++w) o[w] = sv[w] - lse;
  }
}

extern "C" void kernel_launch(void* const* d_in, const int* in_sizes, int n_in,
                              void* d_out, int out_size, void* d_ws, size_t ws_size,
                              hipStream_t stream) {
  const float* support = (const float*)d_in[0];
  const int*   labels  = (const int*)d_in[1];
  const float* query   = (const float*)d_in[2];
  float* out = (float*)d_out;
  char* ws = (char*)d_ws;

  float*          Ghat = (float*)(ws + WS_GH_OFF);
  unsigned short* P    = (unsigned short*)(ws + WS_P_OFF);

  int nq = in_sizes[2] / 1024;          // 16384
  int main_blocks = nq / 16;            // 1024

  hipLaunchKernelGGL(dsn_prep, dim3(85), dim3(256), 0, stream,
                     support, labels, P, Ghat);
  hipLaunchKernelGGL(dsn_main, dim3(main_blocks), dim3(256), 0, stream,
                     query, P, Ghat, out);
}

// Round 20
// 42.922 us; speedup vs baseline: 1.5260x; 1.3023x over previous
//
#include <hip/hip_runtime.h>
#include <stdint.h>

// DSN few-shot classifier, MI355X.
// out[q][w] = log_softmax_w( s_w ),  s_w = z_w^T Ghat_w z_w,
// z_w = M_w^T q (raw support dots),  Ghat = G^{-1} - v v^T/(v^T G v).
//
// R19: effective compute clock is ~200-300MHz (short replay window; fills
// prove mem clock high) -> minimize critical-path CYCLES. Solve chain halved:
// GJ inverse (1.8K cyc) + 16 SHIFTED power iterations (sigma = mean of
// non-dominant eigs of B=Ginv/dmax; ratio 0.65/iter vs 0.92) + 2 plain
// matvecs = ~1.2K cyc, replacing 7 matrix-squarings (~4K cyc). Everything
// else = proven-fastest forms: R13 wide prep, R18 split-K-in-LDS GEMM
// (compact 5.2MB Z, in-LDS split sum), R13 post.
//
// ws layout:
//   [0,      4000)   G    : 5*100 double
//   [4096,   6096)   Ghat : 5*100 float
//   [8192,   172032) P    : 80*1024 bf16 (way w rows 16w..16w+9; rest zero)
//   [262144, 5505024) Z   : [80][16384] float (compact, split-summed)

typedef __attribute__((ext_vector_type(4))) float f32x4;
typedef __attribute__((ext_vector_type(8))) short s16x8;

#define WS_G_OFF    0
#define WS_GH_OFF   4096
#define WS_P_OFF    8192
#define WS_Z_OFF    262144

#define RDL(x, l) __uint_as_float(__builtin_amdgcn_readlane(__float_as_uint(x), (l)))

__device__ __forceinline__ unsigned short f2bf(float f) {
  unsigned int u = __float_as_uint(f);
  u += 0x7FFFu + ((u >> 16) & 1u);   // round-to-nearest-even
  return (unsigned short)(u >> 16);
}

// int64 vs int32 one-hot labels detection (validated R0).
__device__ __forceinline__ bool labels_int64(const int* L) {
  int cnt = 0; bool oddz = true;
  #pragma unroll
  for (int t = 0; t < 20; ++t) {
    int v = L[t];
    if (t & 1) { if (v) oddz = false; }
    else       { if (v) cnt++; }
  }
  return oddz && (cnt == 2);
}

__device__ __forceinline__ int cls_of(const int* L, bool is64, int i) {
  int best = -0x7fffffff, c = 0;
  #pragma unroll
  for (int j = 0; j < 5; ++j) {
    int v = is64 ? L[i * 10 + 2 * j] : L[i * 5 + j];
    if (v > best) { best = v; c = j; }
  }
  return c;
}

// ---- Kernel 1: gram (blocks 0..68) + pack P (blocks 69..148) --------------
__global__ __launch_bounds__(256) void dsn_prep(const float* __restrict__ support,
                                                const int* __restrict__ labels,
                                                double* __restrict__ G,
                                                unsigned short* __restrict__ P) {
  int b = blockIdx.x;
  bool is64 = labels_int64(labels);

  if (b < 69) {                        // ---- gram: one wave per (w,a,b) pair
    int wid  = b * 4 + (threadIdx.x >> 6);
    int lane = threadIdx.x & 63;
    if (wid >= 275) return;
    int w = wid / 55, p = wid % 55;
    int a = 0;
    while (p >= 10 - a) { p -= 10 - a; a++; }
    int bb = a + p;

    int myc = (lane < 50) ? cls_of(labels, is64, lane) : -1;
    unsigned long long mask = __ballot(lane < 50 && myc == w);

    unsigned long long m = mask;
    for (int i = 0; i < a; ++i) m &= m - 1;
    int ia = __ffsll((unsigned long long)m) - 1;
    m = mask;
    for (int i = 0; i < bb; ++i) m &= m - 1;
    int ib = __ffsll((unsigned long long)m) - 1;

    const float* A = support + ia * 1024;
    const float* B = support + ib * 1024;
    double acc = 0.0;
    #pragma unroll
    for (int i = 0; i < 16; ++i) {
      int d = lane + 64 * i;
      acc += (double)A[d] * (double)B[d];
    }
    #pragma unroll
    for (int off = 32; off > 0; off >>= 1) acc += __shfl_xor(acc, off);
    if (lane == 0) {
      G[(w * 10 + a) * 10 + bb] = acc;
      G[(w * 10 + bb) * 10 + a] = acc;
    }
  } else {                             // ---- pack: one block per P row
    int r = b - 69;                    // 0..79
    int w = r >> 4, kk = r & 15;
    int t = threadIdx.x;
    unsigned short* Prow = P + r * 1024;
    if (kk >= 10) {                    // zero-pad rows (block-uniform)
      #pragma unroll
      for (int j = 0; j < 4; ++j) Prow[t + 256 * j] = 0;
      return;
    }
    __shared__ int sid;
    if (t < 64) {
      int myc = (t < 50) ? cls_of(labels, is64, t) : -1;
      unsigned long long mask = __ballot(t < 50 && myc == w);
      if (t == 0) {
        unsigned long long m = mask;
        for (int z = 0; z < kk; ++z) m &= m - 1;
        sid = __ffsll(m) - 1;
      }
    }
    __syncthreads();
    const float* src = support + (size_t)sid * 1024;
    #pragma unroll
    for (int j = 0; j < 4; ++j) Prow[t + 256 * j] = f2bf(src[t + 256 * j]);
  }
}

// ---- Kernel 2: solve (blocks 0..4) + split-K-in-LDS GEMM (blocks 5..1028) --
__global__ __launch_bounds__(256, 4) void dsn_zs(const float* __restrict__ query,
                                                 const unsigned short* __restrict__ P,
                                                 const double* __restrict__ G,
                                                 float* __restrict__ Ghat,
                                                 float* __restrict__ Z) {
  if (blockIdx.x < 5) {
    // ====== solve, register-only, barrier-free (wave 0; R14 GJ + shifted
    // power). ~3.2K-cycle chain vs R14's ~6K. ======
    if (threadIdx.x >= 64) return;
    int w = blockIdx.x;
    int li = threadIdx.x;
    int rr = (li < 10) ? li : 0;
    const double* Gr = G + w * 100 + rr * 10;

    float o[10], g[10], h[10];
    #pragma unroll
    for (int j = 0; j < 10; ++j) {
      o[j] = (float)Gr[j];
      g[j] = o[j];
      h[j] = (li == j) ? 1.f : 0.f;
    }

    // Gauss-Jordan on [G | I] (SPD): h -> G^{-1} row li  (R14 proven)
    #pragma unroll
    for (int k = 0; k < 10; ++k) {
      float piv = 1.f / RDL(g[k], k);
      float pg[10], ph[10];
      #pragma unroll
      for (int j = 0; j < 10; ++j) {
        pg[j] = RDL(g[j], k) * piv;
        ph[j] = RDL(h[j], k) * piv;
      }
      float f = g[k];
      bool isk = (li == k);
      #pragma unroll
      for (int j = 0; j < 10; ++j) {
        g[j] = isk ? pg[j] : g[j] - f * pg[j];
        h[j] = isk ? ph[j] : h[j] - f * ph[j];
      }
    }

    // B = Ginv / diagmax; diag of B per lane
    float b[10];
    float d = h[0];
    #pragma unroll
    for (int k = 1; k < 10; ++k) d = (li == k) ? h[k] : d;
    float dm = RDL(d, 0);
    #pragma unroll
    for (int k = 1; k < 10; ++k) dm = fmaxf(dm, RDL(d, k));
    float rn = 1.f / dm;
    #pragma unroll
    for (int j = 0; j < 10; ++j) b[j] = h[j] * rn;
    float db = d * rn;                 // lane li's diag of B

    // trace, argmax-diag (bv ~= 1 at jmx), shift sigma = mean of others
    int jmx = 0;
    float bv = RDL(db, 0);
    float trB = bv;
    #pragma unroll
    for (int k = 1; k < 10; ++k) {
      float t2 = RDL(db, k);
      trB += t2;
      if (t2 > bv) { bv = t2; jmx = k; }   // uniform
    }
    float sigma = (trB - bv) * (1.f / 9.f);
    sigma = fminf(fmaxf(sigma, 0.f), 0.92f);
    float rs = 1.f / (bv - sigma);     // scale dominant growth to ~1

    // 16 shifted-scaled power iterations from e_jmx (ratio ~0.65/iter)
    float x = (li == jmx) ? 1.f : 0.f;
    #pragma unroll
    for (int it = 0; it < 16; ++it) {
      float xn = 0.f;
      #pragma unroll
      for (int k = 0; k < 10; ++k) xn += b[k] * RDL(x, k);
      x = rs * (xn - sigma * x);
    }
    // 2 plain-B matvecs (kill any min-side contamination) + renorm
    #pragma unroll
    for (int it = 0; it < 2; ++it) {
      float xn = 0.f;
      #pragma unroll
      for (int k = 0; k < 10; ++k) xn += b[k] * RDL(x, k);
      float ax = fabsf(xn);
      float mx = RDL(ax, 0);
      #pragma unroll
      for (int k = 1; k < 10; ++k) mx = fmaxf(mx, RDL(ax, k));
      x = xn * (1.f / mx);
    }
    float v = x;

    // denom = v^T G v (scale-invariant); Ghat = Ginv - v v^T / denom
    float gv = 0.f;
    #pragma unroll
    for (int k = 0; k < 10; ++k) gv += o[k] * RDL(v, k);
    float tn = v * gv;
    float denom = RDL(tn, 0);
    #pragma unroll
    for (int k = 1; k < 10; ++k) denom += RDL(tn, k);
    float rden = 1.f / denom;
    if (li < 10) {
      #pragma unroll
      for (int j = 0; j < 10; ++j)
        Ghat[w * 100 + li * 10 + j] = h[j] - v * RDL(v, j) * rden;
    }
    return;
  }

  // ====== GEMM: block = 16 queries; wave = one 256-elem K-split ===========
  __shared__ float Zsh[4][80][17];     // padded: conflict-free

  int t    = threadIdx.x;
  int wave = t >> 6;                   // K-split 0..3
  int lane = t & 63;
  int q0   = (blockIdx.x - 5) * 16;
  int qrow = lane & 15;
  int kbase = wave * 256 + (lane >> 4) * 8;

  const float* qp = query + (size_t)(q0 + qrow) * 1024 + kbase;
  const unsigned short* up = P + qrow * 1024 + kbase;

  f32x4 acc[5];
  #pragma unroll
  for (int w = 0; w < 5; ++w) acc[w] = (f32x4){0.f, 0.f, 0.f, 0.f};

  #pragma unroll
  for (int kt = 0; kt < 8; ++kt) {     // 256 K-elems, fully unrolled
    const float* qk = qp + kt * 32;
    f32x4 lo = *(const f32x4*)qk;
    f32x4 hi = *(const f32x4*)(qk + 4);
    s16x8 bf;
    bf[0] = (short)f2bf(lo[0]); bf[1] = (short)f2bf(lo[1]);
    bf[2] = (short)f2bf(lo[2]); bf[3] = (short)f2bf(lo[3]);
    bf[4] = (short)f2bf(hi[0]); bf[5] = (short)f2bf(hi[1]);
    bf[6] = (short)f2bf(hi[2]); bf[7] = (short)f2bf(hi[3]);
    const unsigned short* uk = up + kt * 32;
    #pragma unroll
    for (int w = 0; w < 5; ++w) {
      s16x8 av = *(const s16x8*)(uk + w * 16384);   // row w*16 + qrow
      acc[w] = __builtin_amdgcn_mfma_f32_16x16x32_bf16(av, bf, acc[w], 0, 0, 0);
    }
  }

  // park partial z: D[row=s][col=q]; row=(lane>>4)*4+reg, col=lane&15 (m89)
  int rowbase = (lane >> 4) * 4;
  #pragma unroll
  for (int w = 0; w < 5; ++w) {
    #pragma unroll
    for (int r = 0; r < 4; ++r)
      Zsh[wave][w * 16 + rowbase + r][qrow] = acc[w][r];
  }
  __syncthreads();

  // split-sum in LDS, write compact Z (1280 floats; deterministic order)
  #pragma unroll
  for (int idx = 0; idx < 5; ++idx) {
    int e = t + idx * 256;             // 0..1279
    int s = e >> 4, c = e & 15;
    float z = Zsh[0][s][c] + Zsh[1][s][c] + Zsh[2][s][c] + Zsh[3][s][c];
    Z[(size_t)s * 16384 + q0 + c] = z;
  }
}

// ---- Kernel 3: epilogue — quadratic forms + log_softmax (R13 proven) ------
__global__ __launch_bounds__(256) void dsn_post(const float* __restrict__ Ghat,
                                                const float* __restrict__ Z,
                                                float* __restrict__ out) {
  __shared__ float Gh[500];
  int t = threadIdx.x;
  for (int i = t; i < 500; i += 256) Gh[i] = Ghat[i];
  __syncthreads();
  int q = blockIdx.x * 256 + t;

  float zv[50];
  #pragma unroll
  for (int w = 0; w < 5; ++w)
    #pragma unroll
    for (int s = 0; s < 10; ++s)
      zv[w * 10 + s] = Z[(size_t)(w * 16 + s) * 16384 + q];   // coalesced

  float sv[5];
  #pragma unroll
  for (int w = 0; w < 5; ++w) {
    float s = 0.f;
    #pragma unroll
    for (int i = 0; i < 10; ++i) {
      float gz = 0.f;
      #pragma unroll
      for (int j = 0; j < 10; ++j) gz += Gh[w * 100 + i * 10 + j] * zv[w * 10 + j];
      s += zv[w * 10 + i] * gz;
    }
    sv[w] = s;
  }
  float mx = fmaxf(fmaxf(fmaxf(sv[0], sv[1]), fmaxf(sv[2], sv[3])), sv[4]);
  float sum = 0.f;
  #pragma unroll
  for (int w = 0; w < 5; ++w) sum += expf(sv[w] - mx);
  float lse = mx + logf(sum);
  float* o = out + (size_t)q * 5;
  #pragma unroll
  for (int w = 0; w < 5; ++w) o[w] = sv[w] - lse;
}

extern "C" void kernel_launch(void* const* d_in, const int* in_sizes, int n_in,
                              void* d_out, int out_size, void* d_ws, size_t ws_size,
                              hipStream_t stream) {
  const float* support = (const float*)d_in[0];
  const int*   labels  = (const int*)d_in[1];
  const float* query   = (const float*)d_in[2];
  float* out = (float*)d_out;
  char* ws = (char*)d_ws;

  double*         G    = (double*)(ws + WS_G_OFF);
  float*          Ghat = (float*)(ws + WS_GH_OFF);
  unsigned short* P    = (unsigned short*)(ws + WS_P_OFF);
  float*          Z    = (float*)(ws + WS_Z_OFF);

  int nq = in_sizes[2] / 1024;          // 16384
  int zs_blocks = nq / 16 + 5;          // 1024 GEMM blocks + 5 solve
  int post_blocks = nq / 256;           // 64

  hipLaunchKernelGGL(dsn_prep, dim3(149), dim3(256), 0, stream, support, labels, G, P);
  hipLaunchKernelGGL(dsn_zs,   dim3(zs_blocks), dim3(256), 0, stream,
                     query, P, G, Ghat, Z);
  hipLaunchKernelGGL(dsn_post, dim3(post_blocks), dim3(256), 0, stream, Ghat, Z, out);
}